// Round 3
// baseline (160.357 us; speedup 1.0000x reference)
//
#include <hip/hip_runtime.h>
#include <hip/hip_bf16.h>

#define NB 64
#define NL 512
#define ND 128
#define NK 256   // concat(Q,UQ) contraction dim

typedef unsigned short ush;
typedef __attribute__((ext_vector_type(8))) short short8;
typedef __attribute__((ext_vector_type(16))) float f32x16;

__device__ __forceinline__ ush f2bs(float f) {
    union { __hip_bfloat16 h; ush u; } cv;
    cv.h = __float2bfloat16(f);
    return cv.u;
}
__device__ __forceinline__ short8 pack_bf8(float4 a, float4 b) {
    short8 r;
    r[0] = (short)f2bs(a.x); r[1] = (short)f2bs(a.y);
    r[2] = (short)f2bs(a.z); r[3] = (short)f2bs(a.w);
    r[4] = (short)f2bs(b.x); r[5] = (short)f2bs(b.y);
    r[6] = (short)f2bs(b.z); r[7] = (short)f2bs(b.w);
    return r;
}
__device__ __forceinline__ f32x16 zero16() {
    f32x16 z = {0.f,0.f,0.f,0.f,0.f,0.f,0.f,0.f,0.f,0.f,0.f,0.f,0.f,0.f,0.f,0.f};
    return z;
}

// ---------------- Kernel W: convert 5 weight matrices to bf16 ----------------
// grid (16, 5), block 256; each thread converts 4 elems.
__global__ __launch_bounds__(256) void wconv_kernel(
    const float* __restrict__ W0, const float* __restrict__ W1,
    const float* __restrict__ W2, const float* __restrict__ W3,
    const float* __restrict__ W4, ush* __restrict__ Wb)
{
    const int m = blockIdx.y;
    const float* W = (m == 0) ? W0 : (m == 1) ? W1 : (m == 2) ? W2 : (m == 3) ? W3 : W4;
    const int e = (blockIdx.x * 256 + threadIdx.x) * 4;
    float4 v = *(const float4*)(W + e);
    ushort4 o;
    o.x = f2bs(v.x); o.y = f2bs(v.y); o.z = f2bs(v.z); o.w = f2bs(v.w);
    *(ushort4*)(Wb + m * 16384 + e) = o;
}

// ---------------- Kernel P: projections, X read exactly once ----------------
// grid (256 row-tiles of 128, 2 groups), block 256 (4 waves), no LDS.
// group 0: EW -> Q(m0), K(m1), V(m4);  group 1: ES -> UQ(m2), UK(m3)
__global__ __launch_bounds__(256) void proj_kernel(
    const float* __restrict__ EW, const float* __restrict__ ES,
    const ush* __restrict__ Wb,
    const float* __restrict__ b0, const float* __restrict__ b1,
    const float* __restrict__ b2, const float* __restrict__ b3,
    const float* __restrict__ b4,
    ush* __restrict__ QU, ush* __restrict__ KU, ush* __restrict__ Vb)
{
    const int g = blockIdx.y, rt = blockIdx.x;
    const int tid = threadIdx.x, w = tid >> 6, lane = tid & 63;
    const int l5 = lane & 31, hi = lane >> 5;
    const float* X = g ? ES : EW;
    const int rbase = rt * 128 + w * 32;

    // pack this wave's 32 X rows into bf16 A-fragments (read once, reused per m)
    const float* xr = X + (size_t)(rbase + l5) * ND + hi * 8;
    short8 af[8];
    #pragma unroll
    for (int ks = 0; ks < 8; ++ks)
        af[ks] = pack_bf8(*(const float4*)(xr + ks * 16),
                          *(const float4*)(xr + ks * 16 + 4));

    const int nm = g ? 2 : 3;
    for (int mi = 0; mi < nm; ++mi) {
        const int m = g ? (2 + mi) : ((mi == 2) ? 4 : mi);
        const ush* Wm = Wb + m * 16384;
        const float* Bp = (m == 0) ? b0 : (m == 1) ? b1 : (m == 2) ? b2 : (m == 3) ? b3 : b4;
        const float scl = (m == 4) ? 1.0f : 0.044194173824159216f;  // 1/(2*sqrt(128))

        f32x16 acc[4];
        acc[0] = zero16(); acc[1] = zero16(); acc[2] = zero16(); acc[3] = zero16();
        #pragma unroll
        for (int ks = 0; ks < 8; ++ks) {
            #pragma unroll
            for (int nb = 0; nb < 4; ++nb) {   // 4 independent chains
                short8 bf_ = *(const short8*)(Wm + (nb * 32 + l5) * 128 + ks * 16 + hi * 8);
                acc[nb] = __builtin_amdgcn_mfma_f32_32x32x16_bf16(af[ks], bf_, acc[nb], 0, 0, 0);
            }
        }

        ush* dst = (m == 0 || m == 2) ? QU : ((m == 4) ? Vb : KU);
        const int colOff = (m == 2 || m == 3) ? 128 : 0;
        const int pitch  = (m == 4) ? ND : NK;
        #pragma unroll
        for (int nb = 0; nb < 4; ++nb) {
            int n = nb * 32 + l5;
            float bias = Bp[n];
            #pragma unroll
            for (int r = 0; r < 16; ++r) {
                int row = rbase + (r & 3) + 8 * (r >> 2) + 4 * hi;
                dst[(size_t)row * pitch + colOff + n] = f2bs((acc[nb][r] + bias) * scl);
            }
        }
    }
}

// ---------------- Kernel F: fused denom + result ----------------
// grid (8 c-tiles of 64, 64 batches), block 512 (8 waves).
// Phase 1: denom[c] = sum_k exp(alpha[c][k]) for this block's 64 columns.
// Phase 2: out[d][c] = sum_l Vv[d][l] * exp(alpha[l][c]) / denom[c].
__global__ __launch_bounds__(512) void fused_kernel(
    const ush* __restrict__ QU, const ush* __restrict__ KU,
    const ush* __restrict__ Vb, float* __restrict__ out)
{
    __shared__ ush Pt[64 * 136];     // P^T tile [c][l(0..127)], pitch 136
    __shared__ float red[256];       // [kh4][rh2][hi2][r16]
    __shared__ float rdenS[64];
    const int b = blockIdx.y, ct = blockIdx.x, c0 = ct * 64;
    const int tid = threadIdx.x, w = tid >> 6, lane = tid & 63;
    const int l5 = lane & 31, hi = lane >> 5;
    const size_t base  = (size_t)b * NL * NK;
    const size_t vbase = (size_t)b * (ND * NL);

    // ---- Phase 1: denominators for columns c0..c0+63 ----
    {
        const int kh = w >> 1, rh = w & 1;   // k-quarter (128 cols), c-row half (32)
        short8 aq[16];
        const ush* qr = QU + base + (size_t)(c0 + rh * 32 + l5) * NK + hi * 8;
        #pragma unroll
        for (int ks = 0; ks < 16; ++ks) aq[ks] = *(const short8*)(qr + ks * 16);
        float rs[16];
        #pragma unroll
        for (int r = 0; r < 16; ++r) rs[r] = 0.f;
        #pragma unroll
        for (int t = 0; t < 4; ++t) {
            const ush* kr = KU + base + (size_t)(kh * 128 + t * 32 + l5) * NK + hi * 8;
            f32x16 a0 = zero16(), a1 = zero16();
            #pragma unroll
            for (int ks = 0; ks < 16; ks += 2) {
                a0 = __builtin_amdgcn_mfma_f32_32x32x16_bf16(aq[ks],     *(const short8*)(kr + ks * 16),       a0, 0, 0, 0);
                a1 = __builtin_amdgcn_mfma_f32_32x32x16_bf16(aq[ks + 1], *(const short8*)(kr + (ks + 1) * 16), a1, 0, 0, 0);
            }
            #pragma unroll
            for (int r = 0; r < 16; ++r) rs[r] += __expf(a0[r] + a1[r]);
        }
        #pragma unroll
        for (int mk = 1; mk <= 16; mk <<= 1)
            #pragma unroll
            for (int r = 0; r < 16; ++r) rs[r] += __shfl_xor(rs[r], mk, 32);
        if (l5 == 0)
            #pragma unroll
            for (int r = 0; r < 16; ++r) red[((kh * 2 + rh) * 2 + hi) * 16 + r] = rs[r];
    }
    __syncthreads();
    if (tid < 64) {
        int c = tid, rh = c >> 5, cr = c & 31;
        int h2 = (cr >> 2) & 1, rq = cr >> 3, rm = cr & 3, r = rq * 4 + rm;
        float s = 0.f;
        #pragma unroll
        for (int kh = 0; kh < 4; ++kh) s += red[((kh * 2 + rh) * 2 + h2) * 16 + r];
        rdenS[c] = 1.0f / s;
    }
    __syncthreads();

    // ---- Phase 2 ----
    const int lsw  = (w >> 1) * 32;   // alpha l-subtile AND PV d-subtile
    const int csub = (w & 1) * 32;
    const float rden = rdenS[csub + l5];
    const ush* kr  = KU + base + (size_t)(c0 + csub + l5) * NK + hi * 8;
    const ush* vr0 = Vb + vbase + (size_t)(lsw + l5) * NL + hi * 8;
    f32x16 oA = zero16(), oB = zero16();

    for (int it = 0; it < 4; ++it) {
        const int l0 = it * 128;
        if (it) __syncthreads();   // previous PV done reading Pt
        // alpha tile: rows l0+lsw..+31, cols c0+csub..+31, K=256 (2 chains)
        const ush* qr = QU + base + (size_t)(l0 + lsw + l5) * NK + hi * 8;
        f32x16 s0 = zero16(), s1 = zero16();
        #pragma unroll
        for (int ks = 0; ks < 16; ks += 2) {
            s0 = __builtin_amdgcn_mfma_f32_32x32x16_bf16(*(const short8*)(qr + ks * 16),
                                                         *(const short8*)(kr + ks * 16),       s0, 0, 0, 0);
            s1 = __builtin_amdgcn_mfma_f32_32x32x16_bf16(*(const short8*)(qr + (ks + 1) * 16),
                                                         *(const short8*)(kr + (ks + 1) * 16), s1, 0, 0, 0);
        }
        // P = exp(alpha)/denom -> Pt[c][l] as bf16
        #pragma unroll
        for (int q = 0; q < 4; ++q) {
            ushort4 pv;
            pv.x = f2bs(__expf(s0[q * 4 + 0] + s1[q * 4 + 0]) * rden);
            pv.y = f2bs(__expf(s0[q * 4 + 1] + s1[q * 4 + 1]) * rden);
            pv.z = f2bs(__expf(s0[q * 4 + 2] + s1[q * 4 + 2]) * rden);
            pv.w = f2bs(__expf(s0[q * 4 + 3] + s1[q * 4 + 3]) * rden);
            *(ushort4*)(&Pt[(csub + l5) * 136 + lsw + q * 8 + hi * 4]) = pv;
        }
        __syncthreads();
        // PV: d rows lsw+l5, c cols csub, K = this iter's 128 l (2 chains)
        #pragma unroll
        for (int ks = 0; ks < 8; ks += 2) {
            short8 va0 = *(const short8*)(vr0 + l0 + ks * 16);
            short8 pb0 = *(const short8*)(&Pt[(csub + l5) * 136 + ks * 16 + hi * 8]);
            oA = __builtin_amdgcn_mfma_f32_32x32x16_bf16(va0, pb0, oA, 0, 0, 0);
            short8 va1 = *(const short8*)(vr0 + l0 + (ks + 1) * 16);
            short8 pb1 = *(const short8*)(&Pt[(csub + l5) * 136 + (ks + 1) * 16 + hi * 8]);
            oB = __builtin_amdgcn_mfma_f32_32x32x16_bf16(va1, pb1, oB, 0, 0, 0);
        }
    }
    f32x16 oacc = oA + oB;
    #pragma unroll
    for (int r = 0; r < 16; ++r) {
        int d = lsw + (r & 3) + 8 * (r >> 2) + 4 * hi;
        out[vbase + (size_t)d * NL + c0 + csub + l5] = oacc[r];
    }
}

extern "C" void kernel_launch(void* const* d_in, const int* in_sizes, int n_in,
                              void* d_out, int out_size, void* d_ws, size_t ws_size,
                              hipStream_t stream)
{
    const float* EW   = (const float*)d_in[0];
    const float* ES   = (const float*)d_in[1];
    const float* WQ_w = (const float*)d_in[2];
    const float* WQ_b = (const float*)d_in[3];
    const float* WK_w = (const float*)d_in[4];
    const float* WK_b = (const float*)d_in[5];
    const float* UQ_w = (const float*)d_in[6];
    const float* UQ_b = (const float*)d_in[7];
    const float* UK_w = (const float*)d_in[8];
    const float* UK_b = (const float*)d_in[9];
    const float* V_w  = (const float*)d_in[10];
    const float* V_b  = (const float*)d_in[11];

    // ws: QU bf16 16MB | KU bf16 16MB | Vb bf16 8MB | Wb bf16 160KB
    if (ws_size < (size_t)40 * 1024 * 1024 + 5 * 16384 * sizeof(ush)) return;

    char* ws = (char*)d_ws;
    ush* QU = (ush*)ws;
    ush* KU = (ush*)(ws + (size_t)16 * 1024 * 1024);
    ush* Vb = (ush*)(ws + (size_t)32 * 1024 * 1024);
    ush* Wb = (ush*)(ws + (size_t)40 * 1024 * 1024);
    float* outp = (float*)d_out;

    wconv_kernel<<<dim3(16, 5), 256, 0, stream>>>(WQ_w, WK_w, UQ_w, UK_w, V_w, Wb);
    proj_kernel<<<dim3(256, 2), 256, 0, stream>>>(EW, ES, Wb,
                                                  WQ_b, WK_b, UQ_b, UK_b, V_b,
                                                  QU, KU, Vb);
    fused_kernel<<<dim3(8, 64), 512, 0, stream>>>(QU, KU, Vb, outp);
}

// Round 4
// 114.087 us; speedup vs baseline: 1.4056x; 1.4056x over previous
//
#include <hip/hip_runtime.h>
#include <hip/hip_bf16.h>

#define NB 64
#define NL 512
#define ND 128
#define NK 256   // concat(Q,UQ) contraction dim

typedef unsigned short ush;
typedef __attribute__((ext_vector_type(8))) short short8;
typedef __attribute__((ext_vector_type(16))) float f32x16;

// Fragment layouts (bf16), one 32x32x16-MFMA operand chunk per lane:
//  QU_f/KU_f: elem off = ((p*16 + ks)*64 + lane)*8 ; holds row p*32+(lane&31),
//             k = ks*16+(lane>>5)*8 .. +7.  p is GLOBAL row-panel (batch*16 + local).
//  Vb_f:      elem off = ((p*32 + ks)*64 + lane)*8 ; holds Vv row p*32+(lane&31),
//             l = ks*16+(lane>>5)*8 .. +7.  p GLOBAL (batch*4 + local).

__device__ __forceinline__ ush f2bs(float f) {
    union { __hip_bfloat16 h; ush u; } cv;
    cv.h = __float2bfloat16(f);
    return cv.u;
}
__device__ __forceinline__ short8 pack_bf8(float4 a, float4 b) {
    short8 r;
    r[0] = (short)f2bs(a.x); r[1] = (short)f2bs(a.y);
    r[2] = (short)f2bs(a.z); r[3] = (short)f2bs(a.w);
    r[4] = (short)f2bs(b.x); r[5] = (short)f2bs(b.y);
    r[6] = (short)f2bs(b.z); r[7] = (short)f2bs(b.w);
    return r;
}
__device__ __forceinline__ f32x16 zero16() {
    f32x16 z = {0.f,0.f,0.f,0.f,0.f,0.f,0.f,0.f,0.f,0.f,0.f,0.f,0.f,0.f,0.f,0.f};
    return z;
}

// ---------------- Kernel W: convert 5 weight matrices to bf16 ----------------
__global__ __launch_bounds__(256) void wconv_kernel(
    const float* __restrict__ W0, const float* __restrict__ W1,
    const float* __restrict__ W2, const float* __restrict__ W3,
    const float* __restrict__ W4, ush* __restrict__ Wb)
{
    const int m = blockIdx.y;
    const float* W = (m == 0) ? W0 : (m == 1) ? W1 : (m == 2) ? W2 : (m == 3) ? W3 : W4;
    const int e = (blockIdx.x * 256 + threadIdx.x) * 4;
    float4 v = *(const float4*)(W + e);
    ushort4 o;
    o.x = f2bs(v.x); o.y = f2bs(v.y); o.z = f2bs(v.z); o.w = f2bs(v.w);
    *(ushort4*)(Wb + m * 16384 + e) = o;
}

// ---------------- Kernel P: projections -> fragment-native outputs ----------------
// grid (256 row-tiles of 128, 2 groups), block 256 (4 waves).
// group 0: EW -> Q(m0), K(m1), V(m4);  group 1: ES -> UQ(m2), UK(m3)
__global__ __launch_bounds__(256) void proj_kernel(
    const float* __restrict__ EW, const float* __restrict__ ES,
    const ush* __restrict__ Wb,
    const float* __restrict__ b0, const float* __restrict__ b1,
    const float* __restrict__ b2, const float* __restrict__ b3,
    const float* __restrict__ b4,
    ush* __restrict__ QUf, ush* __restrict__ KUf, ush* __restrict__ Vbf)
{
    __shared__ ush lds[16384];   // 32 KB: per-wave 8KB QK tiles / whole-block Vv tile
    const int g = blockIdx.y, rt = blockIdx.x;
    const int tid = threadIdx.x, w = tid >> 6, lane = tid & 63;
    const int l5 = lane & 31, hi = lane >> 5;
    const float* X = g ? ES : EW;
    const int rbase = rt * 128 + w * 32;

    // pack this wave's 32 X rows into bf16 A-fragments (rows stay L1-hot)
    const float* xr = X + (size_t)(rbase + l5) * ND + hi * 8;
    short8 af[8];
    #pragma unroll
    for (int ks = 0; ks < 8; ++ks)
        af[ks] = pack_bf8(*(const float4*)(xr + ks * 16),
                          *(const float4*)(xr + ks * 16 + 4));

    const int nm = g ? 2 : 3;
    for (int mi = 0; mi < nm; ++mi) {
        const int m = g ? (2 + mi) : ((mi == 2) ? 4 : mi);
        const ush* Wm = Wb + m * 16384;
        const float* Bp = (m == 0) ? b0 : (m == 1) ? b1 : (m == 2) ? b2 : (m == 3) ? b3 : b4;
        const float scl = (m == 4) ? 1.0f : 0.044194173824159216f;  // 1/(2*sqrt(128))

        f32x16 acc[4];
        acc[0] = zero16(); acc[1] = zero16(); acc[2] = zero16(); acc[3] = zero16();
        #pragma unroll
        for (int ks = 0; ks < 8; ++ks) {
            #pragma unroll
            for (int nb = 0; nb < 4; ++nb) {
                short8 bf_ = *(const short8*)(Wm + (nb * 32 + l5) * 128 + ks * 16 + hi * 8);
                acc[nb] = __builtin_amdgcn_mfma_f32_32x32x16_bf16(af[ks], bf_, acc[nb], 0, 0, 0);
            }
        }

        if (m != 4) {
            // per-wave LDS transpose (XOR swizzle) -> coalesced fragment stores
            char* Tc = (char*)(lds + w * 4096);   // [32][128] ush, row pitch 256B
            #pragma unroll
            for (int nb = 0; nb < 4; ++nb) {
                float bias = Bp[nb * 32 + l5];
                #pragma unroll
                for (int r = 0; r < 16; ++r) {
                    int row = (r & 3) + 8 * (r >> 2) + 4 * hi;
                    int boff = row * 256 + ((((nb * 32 + l5) * 2)) ^ ((row & 7) << 4));
                    *(ush*)(Tc + boff) = f2bs((acc[nb][r] + bias) * scl);
                }
            }
            ush* dstf = (m == 0 || m == 2) ? QUf : KUf;
            const int p_g = rt * 4 + w;
            const int ko = (m >= 2) ? 8 : 0;
            #pragma unroll
            for (int ks8 = 0; ks8 < 8; ++ks8) {
                int boff = l5 * 256 + ((ks8 * 32 + hi * 16) ^ ((l5 & 7) << 4));
                short8 v = *(const short8*)(Tc + boff);
                *(short8*)(dstf + ((size_t)(p_g * 16 + ko + ks8) * 64 + lane) * 8) = v;
            }
        } else {
            // V: value tile -> Vv layout in block LDS (wave-private row range), then
            // cooperative fragment store of panel #rt.
            char* Lc = (char*)lds;   // [32 d][512 l] ush, row pitch 1024B
            #pragma unroll
            for (int nb = 0; nb < 4; ++nb) {
                float bias = Bp[nb * 32 + l5];
                #pragma unroll
                for (int r = 0; r < 16; ++r) {
                    int row5 = (r & 3) + 8 * (r >> 2) + 4 * hi;
                    int dl = w * 8 + (row5 >> 2);
                    int lcol = (row5 & 3) * 128 + nb * 32 + l5;
                    int boff = dl * 1024 + ((lcol * 2) ^ ((dl & 7) << 4));
                    *(ush*)(Lc + boff) = f2bs(acc[nb][r] + bias);
                }
            }
            __syncthreads();
            #pragma unroll
            for (int it = 0; it < 8; ++it) {
                int chunk = it * 256 + tid;
                int ks = chunk >> 6, ln = chunk & 63;
                int l5b = ln & 31, hib = ln >> 5;
                int boff = l5b * 1024 + ((ks * 32 + hib * 16) ^ ((l5b & 7) << 4));
                short8 v = *(const short8*)(Lc + boff);
                *(short8*)(Vbf + ((size_t)(rt * 32 + ks) * 64 + ln) * 8) = v;
            }
        }
    }
}

// ---------------- Kernel F: fused denom + result ----------------
// grid (64 b, 8 ct): flat id = ct*64+b -> id%8 = b%8 => whole batch on one XCD.
__global__ __launch_bounds__(512) void fused_kernel(
    const ush* __restrict__ QUf, const ush* __restrict__ KUf,
    const ush* __restrict__ Vbf, float* __restrict__ out)
{
    __shared__ ush Pt[64 * 136];     // P^T tile [c][l(0..127)], pitch 136
    __shared__ float red[256];
    __shared__ float rdenS[64];
    const int b = blockIdx.x, ct = blockIdx.y, c0 = ct * 64;
    const int tid = threadIdx.x, w = tid >> 6, lane = tid & 63;
    const int l5 = lane & 31, hi = lane >> 5;
    const ush* Qb = QUf + (size_t)b * 131072;
    const ush* Kb = KUf + (size_t)b * 131072;
    const ush* Vbb = Vbf + (size_t)b * 65536;
    const size_t obase = (size_t)b * (ND * NL);

    // ---- Phase 1: denom for columns c0..c0+63 ----
    {
        const int kh = w >> 1, rh = w & 1;
        short8 aq[16];
        const ush* qp = Qb + (size_t)(ct * 2 + rh) * 8192 + lane * 8;
        #pragma unroll
        for (int ks = 0; ks < 16; ++ks) aq[ks] = *(const short8*)(qp + ks * 512);
        float rs[16];
        #pragma unroll
        for (int r = 0; r < 16; ++r) rs[r] = 0.f;
        #pragma unroll
        for (int t = 0; t < 4; ++t) {
            const ush* kp = Kb + (size_t)(kh * 4 + t) * 8192 + lane * 8;
            f32x16 a0 = zero16(), a1 = zero16();
            #pragma unroll
            for (int ks = 0; ks < 16; ks += 2) {
                a0 = __builtin_amdgcn_mfma_f32_32x32x16_bf16(aq[ks],     *(const short8*)(kp + ks * 512),       a0, 0, 0, 0);
                a1 = __builtin_amdgcn_mfma_f32_32x32x16_bf16(aq[ks + 1], *(const short8*)(kp + (ks + 1) * 512), a1, 0, 0, 0);
            }
            #pragma unroll
            for (int r = 0; r < 16; ++r) rs[r] += __expf(a0[r] + a1[r]);
        }
        #pragma unroll
        for (int mk = 1; mk <= 16; mk <<= 1)
            #pragma unroll
            for (int r = 0; r < 16; ++r) rs[r] += __shfl_xor(rs[r], mk, 32);
        if (l5 == 0)
            #pragma unroll
            for (int r = 0; r < 16; ++r) red[((kh * 2 + rh) * 2 + hi) * 16 + r] = rs[r];
    }
    __syncthreads();
    if (tid < 64) {
        int c = tid, rh = c >> 5, cr = c & 31;
        int h2 = (cr >> 2) & 1, rq = cr >> 3, rm = cr & 3, r = rq * 4 + rm;
        float s = 0.f;
        #pragma unroll
        for (int kh = 0; kh < 4; ++kh) s += red[((kh * 2 + rh) * 2 + h2) * 16 + r];
        rdenS[c] = 1.0f / s;
    }
    __syncthreads();

    // ---- Phase 2 ----
    const int p2 = w >> 1, csub = (w & 1) * 32;
    const float rden = rdenS[csub + l5];
    const ush* kp2 = Kb + (size_t)(ct * 2 + (w & 1)) * 8192 + lane * 8;
    const ush* vp  = Vbb + (size_t)p2 * 16384 + lane * 8;
    f32x16 oA = zero16(), oB = zero16();

    for (int it = 0; it < 4; ++it) {
        if (it) __syncthreads();
        const ush* qp2 = Qb + (size_t)(it * 4 + p2) * 8192 + lane * 8;
        f32x16 s0 = zero16(), s1 = zero16();
        #pragma unroll
        for (int ks = 0; ks < 16; ks += 2) {
            s0 = __builtin_amdgcn_mfma_f32_32x32x16_bf16(*(const short8*)(qp2 + ks * 512),
                                                         *(const short8*)(kp2 + ks * 512),       s0, 0, 0, 0);
            s1 = __builtin_amdgcn_mfma_f32_32x32x16_bf16(*(const short8*)(qp2 + (ks + 1) * 512),
                                                         *(const short8*)(kp2 + (ks + 1) * 512), s1, 0, 0, 0);
        }
        #pragma unroll
        for (int q = 0; q < 4; ++q) {
            ushort4 pv;
            pv.x = f2bs(__expf(s0[q * 4 + 0] + s1[q * 4 + 0]) * rden);
            pv.y = f2bs(__expf(s0[q * 4 + 1] + s1[q * 4 + 1]) * rden);
            pv.z = f2bs(__expf(s0[q * 4 + 2] + s1[q * 4 + 2]) * rden);
            pv.w = f2bs(__expf(s0[q * 4 + 3] + s1[q * 4 + 3]) * rden);
            *(ushort4*)(&Pt[(csub + l5) * 136 + p2 * 32 + q * 8 + hi * 4]) = pv;
        }
        __syncthreads();
        #pragma unroll
        for (int j = 0; j < 8; j += 2) {
            short8 va0 = *(const short8*)(vp + (it * 8 + j) * 512);
            short8 pb0 = *(const short8*)(&Pt[(csub + l5) * 136 + j * 16 + hi * 8]);
            oA = __builtin_amdgcn_mfma_f32_32x32x16_bf16(va0, pb0, oA, 0, 0, 0);
            short8 va1 = *(const short8*)(vp + (it * 8 + j + 1) * 512);
            short8 pb1 = *(const short8*)(&Pt[(csub + l5) * 136 + (j + 1) * 16 + hi * 8]);
            oB = __builtin_amdgcn_mfma_f32_32x32x16_bf16(va1, pb1, oB, 0, 0, 0);
        }
    }
    f32x16 oacc = oA + oB;
    #pragma unroll
    for (int r = 0; r < 16; ++r) {
        int d = p2 * 32 + (r & 3) + 8 * (r >> 2) + 4 * hi;
        out[obase + (size_t)d * NL + c0 + csub + l5] = oacc[r];
    }
}

extern "C" void kernel_launch(void* const* d_in, const int* in_sizes, int n_in,
                              void* d_out, int out_size, void* d_ws, size_t ws_size,
                              hipStream_t stream)
{
    const float* EW   = (const float*)d_in[0];
    const float* ES   = (const float*)d_in[1];
    const float* WQ_w = (const float*)d_in[2];
    const float* WQ_b = (const float*)d_in[3];
    const float* WK_w = (const float*)d_in[4];
    const float* WK_b = (const float*)d_in[5];
    const float* UQ_w = (const float*)d_in[6];
    const float* UQ_b = (const float*)d_in[7];
    const float* UK_w = (const float*)d_in[8];
    const float* UK_b = (const float*)d_in[9];
    const float* V_w  = (const float*)d_in[10];
    const float* V_b  = (const float*)d_in[11];

    // ws: QU_f 16MB | KU_f 16MB | Vb_f 8MB | Wb 160KB
    if (ws_size < (size_t)40 * 1024 * 1024 + 5 * 16384 * sizeof(ush)) return;

    char* ws = (char*)d_ws;
    ush* QUf = (ush*)ws;
    ush* KUf = (ush*)(ws + (size_t)16 * 1024 * 1024);
    ush* Vbf = (ush*)(ws + (size_t)32 * 1024 * 1024);
    ush* Wb  = (ush*)(ws + (size_t)40 * 1024 * 1024);
    float* outp = (float*)d_out;

    wconv_kernel<<<dim3(16, 5), 256, 0, stream>>>(WQ_w, WK_w, UQ_w, UK_w, V_w, Wb);
    proj_kernel<<<dim3(256, 2), 256, 0, stream>>>(EW, ES, Wb,
                                                  WQ_b, WK_b, UQ_b, UK_b, V_b,
                                                  QUf, KUf, Vbf);
    fused_kernel<<<dim3(64, 8), 512, 0, stream>>>(QUf, KUf, Vbf, outp);
}